// Round 2
// baseline (55.603 us; speedup 1.0000x reference)
//
#include <hip/hip_runtime.h>

// y[b,o] = sum_i w[o,i] * (g-1) * exp(-0.5*g^2),  g = s[o,i]*(x[b,i]+c[o,i])
// then BatchNorm over batch (training stats, biased var).
// B=2048, I=256, O=256, fp32. VALU-bound (exp chain); no MFMA applicable.
//
// R1 fix: grid was 256 blocks = 1 block/CU = 1 wave/SIMD (Occupancy 9.7%,
// VALUBusy 48%). Split i-reduction across ISPLIT blocks (grid x4) and shrink
// LDS chunk IC 64->32 (22.5 KB -> 4+ blocks/CU co-resident).

#define BATCH 2048
#define IFEAT 256
#define OFEAT 256

#define BT 64   // batch tile per block
#define OT 32   // out-feature tile per block
#define IC 32   // i chunk staged in LDS
#define LDP 36  // padded row stride (floats): stride == 4 (mod 32) -> measured 0 bank conflicts

#define KLOG2E (-0.7213475204444817f)  // -0.5 * log2(e)

__device__ __forceinline__ float chain4(const float4 s, const float4 c, const float4 w,
                                        const float4 xv, float acc) {
    {
        float g = __builtin_fmaf(s.x, xv.x, c.x);
        float e = __builtin_amdgcn_exp2f(KLOG2E * g * g);
        acc = __builtin_fmaf(w.x * e, g - 1.0f, acc);
    }
    {
        float g = __builtin_fmaf(s.y, xv.y, c.y);
        float e = __builtin_amdgcn_exp2f(KLOG2E * g * g);
        acc = __builtin_fmaf(w.y * e, g - 1.0f, acc);
    }
    {
        float g = __builtin_fmaf(s.z, xv.z, c.z);
        float e = __builtin_amdgcn_exp2f(KLOG2E * g * g);
        acc = __builtin_fmaf(w.z * e, g - 1.0f, acc);
    }
    {
        float g = __builtin_fmaf(s.w, xv.w, c.w);
        float e = __builtin_amdgcn_exp2f(KLOG2E * g * g);
        acc = __builtin_fmaf(w.w * e, g - 1.0f, acc);
    }
    return acc;
}

// grid = (OFEAT/OT, BATCH/BT, P); each z-slice reduces ilen = IFEAT/P i-values
// and writes a partial-sum tile to part + z*B*O (part == y when P == 1).
__global__ __launch_bounds__(256) void xmm_main(
    const float* __restrict__ x, const float* __restrict__ scale,
    const float* __restrict__ bias, const float* __restrict__ weight,
    float* __restrict__ part, int ilen)
{
    __shared__ float xs[BT * LDP];
    __shared__ float ss[OT * LDP];
    __shared__ float cs[OT * LDP];
    __shared__ float wl[OT * LDP];

    const int t  = threadIdx.x;
    const int to = t & 15;    // o-lane
    const int tw = t >> 4;    // b-group (0..15), 4 rows each
    const int o0 = blockIdx.x * OT;
    const int b0 = blockIdx.y * BT;
    const int i0 = blockIdx.z * ilen;

    float acc[4][2];
#pragma unroll
    for (int j = 0; j < 4; ++j) { acc[j][0] = 0.0f; acc[j][1] = 0.0f; }

    for (int c = 0; c < ilen / IC; ++c) {
        const int ib = i0 + c * IC;
        __syncthreads();
        // ---- stage x: 64 rows x 8 float4 (2 per thread) ----
        {
            int row = t >> 3, c4 = t & 7;
            *(float4*)(xs + row * LDP + c4 * 4) =
                *(const float4*)(x + (b0 + row) * IFEAT + ib + c4 * 4);
            row += 32;
            *(float4*)(xs + row * LDP + c4 * 4) =
                *(const float4*)(x + (b0 + row) * IFEAT + ib + c4 * 4);
        }
        // ---- stage params: 32 rows x 8 float4 (1 per thread), fold c := s*bias ----
        {
            const int row = t >> 3, c4 = t & 7;
            const int gidx = (o0 + row) * IFEAT + ib + c4 * 4;
            float4 s4 = *(const float4*)(scale + gidx);
            float4 b4 = *(const float4*)(bias + gidx);
            float4 w4 = *(const float4*)(weight + gidx);
            float4 sc;
            sc.x = s4.x * b4.x; sc.y = s4.y * b4.y;
            sc.z = s4.z * b4.z; sc.w = s4.w * b4.w;
            *(float4*)(ss + row * LDP + c4 * 4) = s4;
            *(float4*)(cs + row * LDP + c4 * 4) = sc;
            *(float4*)(wl + row * LDP + c4 * 4) = w4;
        }
        __syncthreads();

#pragma unroll
        for (int ii = 0; ii < IC / 4; ++ii) {
            float4 sA = *(const float4*)(ss + to * LDP + ii * 4);
            float4 cA = *(const float4*)(cs + to * LDP + ii * 4);
            float4 wA = *(const float4*)(wl + to * LDP + ii * 4);
            float4 sB = *(const float4*)(ss + (to + 16) * LDP + ii * 4);
            float4 cB = *(const float4*)(cs + (to + 16) * LDP + ii * 4);
            float4 wB = *(const float4*)(wl + (to + 16) * LDP + ii * 4);
#pragma unroll
            for (int j = 0; j < 4; ++j) {
                float4 xv = *(const float4*)(xs + (tw * 4 + j) * LDP + ii * 4);
                acc[j][0] = chain4(sA, cA, wA, xv, acc[j][0]);
                acc[j][1] = chain4(sB, cB, wB, xv, acc[j][1]);
            }
        }
    }

    float* dst = part + (size_t)blockIdx.z * (BATCH * OFEAT);
#pragma unroll
    for (int j = 0; j < 4; ++j) {
        const int b = b0 + tw * 4 + j;
        dst[b * OFEAT + o0 + to]      = acc[j][0];
        dst[b * OFEAT + o0 + to + 16] = acc[j][1];
    }
}

// Sum P partial slices into y. grid = 256 blocks x 256 thr, 8 rows/block.
__global__ __launch_bounds__(256) void xmm_combine(
    const float* __restrict__ part, float* __restrict__ y, int P)
{
    const int t = threadIdx.x;
    const int r0 = blockIdx.x * 8;
    for (int j = 0; j < 8; ++j) {
        const int idx = (r0 + j) * OFEAT + t;
        float v = part[idx];
        for (int p = 1; p < P; ++p) v += part[(size_t)p * (BATCH * OFEAT) + idx];
        y[idx] = v;
    }
}

// Column-reduce y over batch: one block per o. Writes A = gamma*rstd,
// Bc = beta - mean*A so apply is a single fma.
__global__ __launch_bounds__(256) void xmm_stats(
    const float* __restrict__ y, const float* __restrict__ gamma,
    const float* __restrict__ beta, float* __restrict__ A, float* __restrict__ Bc)
{
    const int o = blockIdx.x;
    const int t = threadIdx.x;
    float s = 0.0f, q = 0.0f;
#pragma unroll
    for (int j = 0; j < BATCH / 256; ++j) {
        float v = y[(t + j * 256) * OFEAT + o];
        s += v; q += v * v;
    }
#pragma unroll
    for (int mask = 1; mask <= 32; mask <<= 1) {
        s += __shfl_xor(s, mask);
        q += __shfl_xor(q, mask);
    }
    __shared__ float rs[4], rq[4];
    if ((t & 63) == 0) { rs[t >> 6] = s; rq[t >> 6] = q; }
    __syncthreads();
    if (t == 0) {
        s = rs[0] + rs[1] + rs[2] + rs[3];
        q = rq[0] + rq[1] + rq[2] + rq[3];
        const float m = s * (1.0f / (float)BATCH);
        const float v = q * (1.0f / (float)BATCH) - m * m;
        const float r = rsqrtf(v + 1e-5f);
        const float a = gamma[o] * r;
        A[o]  = a;
        Bc[o] = __builtin_fmaf(-m, a, beta[o]);
    }
}

__global__ __launch_bounds__(256) void xmm_apply(
    float* __restrict__ y, const float* __restrict__ A, const float* __restrict__ Bc)
{
    const int i4 = blockIdx.x * 256 + threadIdx.x;   // 131072 float4s
    const int o4 = i4 & (OFEAT / 4 - 1);
    float4 v = ((float4*)y)[i4];
    const float4 a  = ((const float4*)A)[o4];
    const float4 bc = ((const float4*)Bc)[o4];
    v.x = __builtin_fmaf(v.x, a.x, bc.x);
    v.y = __builtin_fmaf(v.y, a.y, bc.y);
    v.z = __builtin_fmaf(v.z, a.z, bc.z);
    v.w = __builtin_fmaf(v.w, a.w, bc.w);
    ((float4*)y)[i4] = v;
}

extern "C" void kernel_launch(void* const* d_in, const int* in_sizes, int n_in,
                              void* d_out, int out_size, void* d_ws, size_t ws_size,
                              hipStream_t stream) {
    const float* x      = (const float*)d_in[0];
    const float* scale  = (const float*)d_in[1];
    const float* bias   = (const float*)d_in[2];
    const float* weight = (const float*)d_in[3];
    const float* gamma  = (const float*)d_in[4];
    const float* beta   = (const float*)d_in[5];
    float* y  = (float*)d_out;
    float* ws = (float*)d_ws;

    const size_t BO = (size_t)BATCH * OFEAT;           // 524288 floats
    const size_t abbytes = 2 * OFEAT * sizeof(float);  // A + Bc

    // Pick i-split by available workspace: parts (P*BO floats) + A/Bc tail.
    int P;
    if      (ws_size >= 4 * BO * sizeof(float) + abbytes) P = 4;
    else if (ws_size >= 2 * BO * sizeof(float) + abbytes) P = 2;
    else                                                  P = 1;

    float* part = (P == 1) ? y : ws;
    float* A  = (P == 1) ? ws : ws + P * BO;
    float* Bc = A + OFEAT;

    xmm_main<<<dim3(OFEAT / OT, BATCH / BT, P), 256, 0, stream>>>(
        x, scale, bias, weight, part, IFEAT / P);
    if (P > 1)
        xmm_combine<<<BATCH / 8, 256, 0, stream>>>(part, y, P);
    xmm_stats<<<OFEAT, 256, 0, stream>>>(y, gamma, beta, A, Bc);
    xmm_apply<<<(BATCH * OFEAT / 4) / 256, 256, 0, stream>>>(y, A, Bc);
}